// Round 11
// baseline (743.972 us; speedup 1.0000x reference)
//
#include <hip/hip_runtime.h>
#include <cstdint>
#include <cstddef>

typedef __attribute__((ext_vector_type(8))) short short8;
typedef __attribute__((ext_vector_type(4))) float f32x4;

#define DEV __device__ __forceinline__

DEV unsigned short f2bf(float f) {
  unsigned int u = __float_as_uint(f);
  u += 0x7fffu + ((u >> 16) & 1u);   // round-to-nearest-even
  return (unsigned short)(u >> 16);
}

DEV unsigned int pk2(float a, float b) {
  return (unsigned int)f2bf(a) | ((unsigned int)f2bf(b) << 16);
}

constexpr int NROW = 12288;

// ---------------- P0: t0T = (x @ W0)^T  -> bf16 [128][12288] ----------------
__global__ __launch_bounds__(256) void xw_kernel(
    const float* __restrict__ x, const float* __restrict__ W0,
    unsigned short* __restrict__ t0T) {
  __shared__ float sW[128 * 128];
  __shared__ float sx[16][128];
  const int t = threadIdx.x;
  for (int i = t; i < 128 * 128; i += 256) sW[i] = W0[i];
  const int r0 = blockIdx.x * 16;
  for (int i = t; i < 16 * 128; i += 256)
    sx[i >> 7][i & 127] = x[(size_t)(r0 + (i >> 7)) * 128 + (i & 127)];
  __syncthreads();
  const int c = t & 127;   // output column 0..127
  const int rg = t >> 7;   // row group: rows rg*8 .. rg*8+7
  float acc[8] = {0, 0, 0, 0, 0, 0, 0, 0};
  for (int k = 0; k < 128; ++k) {
    float w = sW[k * 128 + c];
#pragma unroll
    for (int j = 0; j < 8; ++j) acc[j] += sx[rg * 8 + j][k] * w;
  }
  uint4 o;
  o.x = pk2(acc[0], acc[1]);
  o.y = pk2(acc[2], acc[3]);
  o.z = pk2(acc[4], acc[5]);
  o.w = pk2(acc[6], acc[7]);
  *(uint4*)(t0T + (size_t)c * NROW + r0 + rg * 8) = o;
}

// ------------- big GEMM: part[split] = adj_chunk @ t   (bf16 MFMA) -----------
// A: [12288][12288] f32 (adj), BT: [H][12288] bf16 (t transposed)
// part: [KSPLIT][12288][H] f32
// Structure = R10 (best) with ONE structural change: B staging is
// global->reg->ds_write (T14 issue-early/write-late) instead of
// global_load_lds. B(s+2) issued at step s into the reg set freed by the
// step-(s-1) LDS write; B(s+1) regs ds_written during step s (compiler
// auto-inserts exact counted vmcnt for the reg deps). Every barrier is now
// lgkmcnt(0)-ONLY: A bursts + B(s+2) loads stay in flight across ALL
// barriers (previously 2 of 3 barriers drained vmcnt(0) because DMA-written
// LDS could only be handed over by draining the queue).
template <int H>
__global__ __launch_bounds__(256, 3) void gcn_gemm(
    const float* __restrict__ A, const unsigned short* __restrict__ BT,
    float* __restrict__ part) {
  constexpr int KSPLIT = 4;
  constexpr int BM = 64, BK = 64;
  constexpr int WN = (H >= 64) ? 2 : 1;
  constexpr int WM = 4 / WN;
  constexpr int MR = BM / (WM * 16);
  constexpr int NR = H / (WN * 16);
  constexpr int NB = H / 32;                    // B loads per thread/step
  constexpr int KSTEPS = (NROW / KSPLIT) / BK;  // 48 = 3*16
  constexpr int NSUP = KSTEPS / 3;              // 16 supersteps
  constexpr int BBYTES = H * 128;               // one B^T tile (bf16)
  static_assert(KSTEPS % 3 == 0, "");

  __shared__ alignas(16) char lds[16384 + 2 * BBYTES];
  char* ldsB = lds + 16384;

  const int t = threadIdx.x;
  // ---- split-per-XCD remap (grid = 768 = 8 XCD * 96) ----
  const int xcd = blockIdx.x & 7;
  const int idx = blockIdx.x >> 3;          // 0..95
  const int split = xcd >> 1;               // one split per XCD
  const int bm = ((xcd & 1) ? 96 : 0) + idx;
  const int k0 = split * (NROW / KSPLIT);

  // ---- A staging (R10): 4 threads/row (r=t>>2,q=t&3); load (j,i) reads
  //      bytes j*256 + i*64 + q*16 of the row (q-lanes merge to 64B) ----
  const int r = t >> 2, q = t & 3;
  const float* aptr = A + (size_t)(bm * BM + r) * NROW + k0;
  const int sw = (r & 7) << 4;

  // ---- B^T staging source: swizzle folded into global address ----
  const int nB0 = t >> 3;                    // row within round (+32/round)
  const int wB = (t & 7) ^ (nB0 & 7);        // pre-swizzled 16B chunk in row
  const unsigned short* bptr = BT + (size_t)nB0 * NROW + k0 + wB * 8;
  const int wid = t >> 6;

  // ---- MFMA fragment LDS offsets ----
  const int lane = t & 63;
  const int l15 = lane & 15;
  const int loct = lane >> 4;
  const int wm = wid / WN;
  const int wn = wid % WN;
  int aoff[MR][2], boff[NR][2];
#pragma unroll
  for (int m = 0; m < MR; ++m)
#pragma unroll
    for (int kk = 0; kk < 2; ++kk) {
      int row = wm * (MR * 16) + m * 16 + l15;
      aoff[m][kk] = (row * 128 + kk * 64 + loct * 16) ^ ((row & 7) << 4);
    }
#pragma unroll
  for (int n = 0; n < NR; ++n)
#pragma unroll
    for (int kk = 0; kk < 2; ++kk) {
      int nn = wn * (NR * 16) + n * 16 + l15;
      boff[n][kk] = (nn * 128 + kk * 64 + loct * 16) ^ ((nn & 7) << 4);
    }

  f32x4 acc[MR][NR];
#pragma unroll
  for (int m = 0; m < MR; ++m)
#pragma unroll
    for (int n = 0; n < NR; ++n) acc[m][n] = {0.f, 0.f, 0.f, 0.f};

  f32x4 av[12];            // one superstep's A (48 VGPR); av[j*4+i]
  uint4 br0[NB], br1[NB];  // B reg sets: set[k&1] holds B(k)

  auto issueSuper = [&](int S) {
#pragma unroll
    for (int j = 0; j < 3; ++j)
#pragma unroll
      for (int i = 0; i < 4; ++i)
        av[j * 4 + i] =
            *(const f32x4*)(aptr + S * 192 + j * 64 + i * 16 + q * 4);
  };
  auto glBreg = [&](uint4* br, int s) {   // issue B(s) global reads
    if (s >= KSTEPS) return;
#pragma unroll
    for (int j = 0; j < NB; ++j)
      br[j] = *(const uint4*)(bptr + (size_t)j * 32 * NROW + s * BK);
  };
  auto wrB = [&](const uint4* br, int buf) {  // B regs -> LDS buf
#pragma unroll
    for (int j = 0; j < NB; ++j)
      *(uint4*)(ldsB + buf * BBYTES + j * 4096 + t * 16) = br[j];
  };
  auto cvtWrite = [&](int j, int buf) {   // write A slice j into A buf
    char* wb = lds + buf * 8192;
#pragma unroll
    for (int i = 0; i < 4; ++i) {
      uint2 w;
      w.x = pk2(av[j * 4 + i].x, av[j * 4 + i].y);
      w.y = pk2(av[j * 4 + i].z, av[j * 4 + i].w);
      *(uint2*)(wb + ((r * 128 + i * 32 + q * 8) ^ sw)) = w;
    }
  };
  auto compute = [&](int buf) {
    const char* lA = lds + buf * 8192;
    const char* lB = ldsB + buf * BBYTES;
#pragma unroll
    for (int kk = 0; kk < 2; ++kk) {
      short8 af[MR], bfv[NR];
#pragma unroll
      for (int m = 0; m < MR; ++m) af[m] = *(const short8*)(lA + aoff[m][kk]);
#pragma unroll
      for (int n = 0; n < NR; ++n) bfv[n] = *(const short8*)(lB + boff[n][kk]);
#pragma unroll
      for (int m = 0; m < MR; ++m)
#pragma unroll
        for (int n = 0; n < NR; ++n)
          acc[m][n] = __builtin_amdgcn_mfma_f32_16x16x32_bf16(
              af[m], bfv[n], acc[m][n], 0, 0, 0);
    }
  };

#define BARRIER_LG                                         \
  asm volatile("s_waitcnt lgkmcnt(0)" ::: "memory");       \
  __builtin_amdgcn_s_barrier();                            \
  __builtin_amdgcn_sched_barrier(0);

  // ---- Prologue: B(0)->regs->LDS0; A set0 burst; B(1) in flight ----
  glBreg(br0, 0);
  issueSuper(0);
  wrB(br0, 0);             // auto-wait retires B(0); A stays in flight
  glBreg(br1, 1);          // B(1) issued, flies across the barrier
  cvtWrite(0, 0);          // auto-wait for av[0..1]; B(1) stays in flight
  BARRIER_LG;

  // ---- Main loop: step s = 3S+j; buf b = s&1 ----
  for (int S = 0; S < NSUP; ++S) {
    const int b = S & 1;   // parity of step 3S
    const int s = 3 * S;
    // -- step s (j=0): compute buf b; stage B(s+1),A(s+1) -> buf b^1 --
    glBreg((s & 1) ? br1 : br0, s + 2);
    compute(b);
    wrB(((s + 1) & 1) ? br1 : br0, b ^ 1);
    cvtWrite(1, b ^ 1);
    BARRIER_LG;
    // -- step s+1 (j=1): compute b^1; stage (s+2)->b; burst-issue set S+1 --
    glBreg(((s + 1) & 1) ? br1 : br0, s + 3);
    compute(b ^ 1);
    wrB((s & 1) ? br1 : br0, b);          // B(s+2) regs (parity s)
    cvtWrite(2, b);
    if (S + 1 < NSUP) issueSuper(S + 1);  // 12 A loads fly across barrier
    BARRIER_LG;
    // -- step s+2 (j=2): compute b; stage (s+3)->b^1 from NEW A set --
    if (S + 1 < NSUP) {
      glBreg((s & 1) ? br1 : br0, s + 4);
      compute(b);
      wrB(((s + 1) & 1) ? br1 : br0, b ^ 1);  // B(s+3) regs (parity s+1)
      cvtWrite(0, b ^ 1);                      // auto-waits new av set
      BARRIER_LG;
    } else {
      compute(b);          // final step (s+2 = 47), nothing to stage
    }
  }
#undef BARRIER_LG

  float* pout = part + ((size_t)split * NROW + (size_t)bm * BM) * H;
#pragma unroll
  for (int m = 0; m < MR; ++m) {
    const int row = wm * (MR * 16) + m * 16 + loct * 4;
#pragma unroll
    for (int n = 0; n < NR; ++n) {
      const int col = wn * (NR * 16) + n * 16 + l15;
#pragma unroll
      for (int rr = 0; rr < 4; ++rr)
        pout[(size_t)(row + rr) * H + col] = acc[m][n][rr];
    }
  }
}

// ------- reduce: sum splits + bias + LN + (leaky) + @Wnext -> t_next^T -------
template <int H, int H2, bool ACT>
__global__ __launch_bounds__(256) void reduce_ln(
    const float* __restrict__ part, const float* __restrict__ bias,
    const float* __restrict__ g, const float* __restrict__ be,
    const float* __restrict__ Wn, unsigned short* __restrict__ tT) {
  __shared__ float sW[H * H2];
  __shared__ float sh[4][H];
  const int t = threadIdx.x;
  for (int i = t; i < H * H2; i += 256) sW[i] = Wn[i];
  __syncthreads();

  const int wid = t >> 6, lane = t & 63;
  const int row = blockIdx.x * 4 + wid;
  constexpr int CPL = H / 64;
  float v[CPL];
#pragma unroll
  for (int c = 0; c < CPL; ++c) {
    const int col = lane + c * 64;
    float s = bias[col];
#pragma unroll
    for (int sp = 0; sp < 4; ++sp)
      s += part[((size_t)sp * NROW + row) * H + col];
    v[c] = s;
  }
  float sum = 0;
#pragma unroll
  for (int c = 0; c < CPL; ++c) sum += v[c];
#pragma unroll
  for (int o = 32; o > 0; o >>= 1) sum += __shfl_xor(sum, o);
  const float mu = sum / H;
  float vs = 0;
#pragma unroll
  for (int c = 0; c < CPL; ++c) { float d = v[c] - mu; vs += d * d; }
#pragma unroll
  for (int o = 32; o > 0; o >>= 1) vs += __shfl_xor(vs, o);
  const float rstd = rsqrtf(vs / H + 1e-5f);
#pragma unroll
  for (int c = 0; c < CPL; ++c) {
    const int col = lane + c * 64;
    float h = (v[c] - mu) * rstd * g[col] + be[col];
    if (ACT) h = (h > 0.f) ? h : 0.01f * h;
    sh[wid][col] = h;
  }
  __syncthreads();
  if (lane < H2) {
    float d = 0;
#pragma unroll 8
    for (int k = 0; k < H; ++k) d += sh[wid][k] * sW[k * H2 + lane];
    tT[(size_t)lane * NROW + row] = f2bf(d);
  }
}

// ------- final: sum splits + bias + LN + leaky + @Wl+bl + log_softmax -------
__global__ __launch_bounds__(256) void reduce_final(
    const float* __restrict__ part, const float* __restrict__ bias,
    const float* __restrict__ g, const float* __restrict__ be,
    const float* __restrict__ Wl, const float* __restrict__ bl,
    float* __restrict__ out) {
  __shared__ float sW[32 * 20];
  __shared__ float sbl[20];
  __shared__ float sh[4][32];
  __shared__ float sl[4][20];
  const int t = threadIdx.x;
  for (int i = t; i < 640; i += 256) sW[i] = Wl[i];
  if (t < 20) sbl[t] = bl[t];
  __syncthreads();
  const int wid = t >> 6, lane = t & 63;
  const int row = blockIdx.x * 4 + wid;
  const int col = lane & 31;  // lanes 32..63 duplicate cols 0..31
  float v = bias[col];
#pragma unroll
  for (int sp = 0; sp < 4; ++sp)
    v += part[((size_t)sp * NROW + row) * 32 + col];
  float sum = v;
#pragma unroll
  for (int o = 32; o > 0; o >>= 1) sum += __shfl_xor(sum, o);
  const float mu = sum / 64.f;  // values duplicated 2x across the wave
  float d0 = v - mu;
  float vs = d0 * d0;
#pragma unroll
  for (int o = 32; o > 0; o >>= 1) vs += __shfl_xor(vs, o);
  const float rstd = rsqrtf(vs / 64.f + 1e-5f);
  float h = (v - mu) * rstd * g[col] + be[col];
  h = (h > 0.f) ? h : 0.01f * h;
  if (lane < 32) sh[wid][col] = h;
  __syncthreads();
  if (lane < 20) {
    float lg = sbl[lane];
#pragma unroll
    for (int k = 0; k < 32; ++k) lg += sh[wid][k] * sW[k * 20 + lane];
    sl[wid][lane] = lg;
  }
  __syncthreads();
  if (lane < 20) {
    float mx = -1e30f;
#pragma unroll
    for (int k = 0; k < 20; ++k) mx = fmaxf(mx, sl[wid][k]);
    float se = 0.f;
#pragma unroll
    for (int k = 0; k < 20; ++k) se += expf(sl[wid][k] - mx);
    out[(size_t)row * 20 + lane] = sl[wid][lane] - mx - logf(se);
  }
}

extern "C" void kernel_launch(void* const* d_in, const int* in_sizes, int n_in,
                              void* d_out, int out_size, void* d_ws,
                              size_t ws_size, hipStream_t stream) {
  const float* x    = (const float*)d_in[0];
  const float* adj0 = (const float*)d_in[1];
  const float* adj1 = (const float*)d_in[2];
  const float* adj2 = (const float*)d_in[3];
  const float* W0   = (const float*)d_in[4];
  const float* b0   = (const float*)d_in[5];
  const float* W1   = (const float*)d_in[6];
  const float* b1   = (const float*)d_in[7];
  const float* W2   = (const float*)d_in[8];
  const float* b2   = (const float*)d_in[9];
  const float* g0   = (const float*)d_in[10];
  const float* be0  = (const float*)d_in[11];
  const float* g1   = (const float*)d_in[12];
  const float* be1  = (const float*)d_in[13];
  const float* g2   = (const float*)d_in[14];
  const float* be2  = (const float*)d_in[15];
  const float* Wl   = (const float*)d_in[16];
  const float* bl   = (const float*)d_in[17];
  float* out = (float*)d_out;

  char* ws = (char*)d_ws;
  float* part =          (float*)(ws);                      // 4*12288*128*4 = 25165824 B
  unsigned short* t0T = (unsigned short*)(ws + 25165824);   // 128*12288*2 = 3145728 B
  unsigned short* t1T = (unsigned short*)(ws + 25165824 + 3145728);          // 1572864 B
  unsigned short* t2T = (unsigned short*)(ws + 25165824 + 3145728 + 1572864); // 786432 B

  xw_kernel<<<NROW / 16, 256, 0, stream>>>(x, W0, t0T);
  gcn_gemm<128><<<(NROW / 64) * 4, 256, 0, stream>>>(adj0, t0T, part);
  reduce_ln<128, 64, false><<<NROW / 4, 256, 0, stream>>>(part, b0, g0, be0, W1, t1T);
  gcn_gemm<64><<<(NROW / 64) * 4, 256, 0, stream>>>(adj1, t1T, part);
  reduce_ln<64, 32, true><<<NROW / 4, 256, 0, stream>>>(part, b1, g1, be1, W2, t2T);
  gcn_gemm<32><<<(NROW / 64) * 4, 256, 0, stream>>>(adj2, t2T, part);
  reduce_final<<<NROW / 4, 256, 0, stream>>>(part, b2, g2, be2, Wl, bl, out);
}

// Round 12
// 451.090 us; speedup vs baseline: 1.6493x; 1.6493x over previous
//
#include <hip/hip_runtime.h>
#include <cstdint>
#include <cstddef>

typedef __attribute__((ext_vector_type(8))) short short8;
typedef __attribute__((ext_vector_type(4))) float f32x4;

#define DEV __device__ __forceinline__

DEV unsigned short f2bf(float f) {
  unsigned int u = __float_as_uint(f);
  u += 0x7fffu + ((u >> 16) & 1u);   // round-to-nearest-even
  return (unsigned short)(u >> 16);
}

DEV unsigned int pk2(float a, float b) {
  return (unsigned int)f2bf(a) | ((unsigned int)f2bf(b) << 16);
}

// async 16B global -> LDS (wave-uniform LDS base; HW adds lane*16)
DEV void glds16(const void* g, void* l) {
  __builtin_amdgcn_global_load_lds(
      (const __attribute__((address_space(1))) void*)g,
      (__attribute__((address_space(3))) void*)l, 16, 0, 0);
}

constexpr int NROW = 12288;

// ---------------- P0: t0T = (x @ W0)^T  -> bf16 [128][12288] ----------------
__global__ __launch_bounds__(256) void xw_kernel(
    const float* __restrict__ x, const float* __restrict__ W0,
    unsigned short* __restrict__ t0T) {
  __shared__ float sW[128 * 128];
  __shared__ float sx[16][128];
  const int t = threadIdx.x;
  for (int i = t; i < 128 * 128; i += 256) sW[i] = W0[i];
  const int r0 = blockIdx.x * 16;
  for (int i = t; i < 16 * 128; i += 256)
    sx[i >> 7][i & 127] = x[(size_t)(r0 + (i >> 7)) * 128 + (i & 127)];
  __syncthreads();
  const int c = t & 127;   // output column 0..127
  const int rg = t >> 7;   // row group: rows rg*8 .. rg*8+7
  float acc[8] = {0, 0, 0, 0, 0, 0, 0, 0};
  for (int k = 0; k < 128; ++k) {
    float w = sW[k * 128 + c];
#pragma unroll
    for (int j = 0; j < 8; ++j) acc[j] += sx[rg * 8 + j][k] * w;
  }
  uint4 o;
  o.x = pk2(acc[0], acc[1]);
  o.y = pk2(acc[2], acc[3]);
  o.z = pk2(acc[4], acc[5]);
  o.w = pk2(acc[6], acc[7]);
  *(uint4*)(t0T + (size_t)c * NROW + r0 + rg * 8) = o;
}

// ------------- big GEMM: part[split] = adj_chunk @ t   (bf16 MFMA) -----------
// A: [12288][12288] f32 (adj), BT: [H][12288] bf16 (t transposed)
// part: [KSPLIT][12288][H] f32
// R10 configuration (best, 449.2 us): superstep A bursts (768B contiguous
// per row per superstep), per-instruction A request merge (4 q-lanes cover
// one 64B segment), B via global_load_lds double-buffer (swizzle folded
// into per-lane global source), raw s_barrier + counted vmcnt (A bursts fly
// across the superstep-issue barrier), split-per-XCD block remap.
// R11's reg-staged B (T14) regressed 66% (VGPR spill + in-order vmcnt
// retiring the A burst) — do not revisit.
template <int H>
__global__ __launch_bounds__(256, 3) void gcn_gemm(
    const float* __restrict__ A, const unsigned short* __restrict__ BT,
    float* __restrict__ part) {
  constexpr int KSPLIT = 4;
  constexpr int BM = 64, BK = 64;
  constexpr int WN = (H >= 64) ? 2 : 1;
  constexpr int WM = 4 / WN;
  constexpr int MR = BM / (WM * 16);
  constexpr int NR = H / (WN * 16);
  constexpr int NB = H / 32;                    // B DMA rounds (per thread)
  constexpr int KSTEPS = (NROW / KSPLIT) / BK;  // 48 = 3*16
  constexpr int NSUP = KSTEPS / 3;              // 16 supersteps
  constexpr int BBYTES = H * 128;               // one B^T tile (bf16)
  static_assert(KSTEPS % 3 == 0, "");

  __shared__ alignas(16) char lds[16384 + 2 * BBYTES];
  char* ldsB = lds + 16384;

  const int t = threadIdx.x;
  // ---- split-per-XCD remap (grid = 768 = 8 XCD * 96) ----
  const int xcd = blockIdx.x & 7;
  const int idx = blockIdx.x >> 3;          // 0..95
  const int split = xcd >> 1;               // one split per XCD
  const int bm = ((xcd & 1) ? 96 : 0) + idx;
  const int k0 = split * (NROW / KSPLIT);

  // ---- A staging: 4 threads/row (r=t>>2, q=t&3). Superstep = 3 steps x
  //      64 floats. Load (j,i): bytes j*256 + i*64 + q*16 of the row ->
  //      per-instruction the 4 q-lanes are CONTIGUOUS 64B (request merge).
  const int r = t >> 2, q = t & 3;
  const float* aptr = A + (size_t)(bm * BM + r) * NROW + k0;
  const int sw = (r & 7) << 4;

  // ---- B^T staging source: swizzle folded into global address ----
  const int nB0 = t >> 3;                    // row within round (+32/round)
  const int wB = (t & 7) ^ (nB0 & 7);        // pre-swizzled 16B chunk in row
  const unsigned short* bptr = BT + (size_t)nB0 * NROW + k0 + wB * 8;
  const int wid = t >> 6;
  char* ldsBw = ldsB + wid * 1024;           // wave-uniform B DMA base

  // ---- MFMA fragment LDS offsets ----
  const int lane = t & 63;
  const int l15 = lane & 15;
  const int loct = lane >> 4;
  const int wm = wid / WN;
  const int wn = wid % WN;
  int aoff[MR][2], boff[NR][2];
#pragma unroll
  for (int m = 0; m < MR; ++m)
#pragma unroll
    for (int kk = 0; kk < 2; ++kk) {
      int row = wm * (MR * 16) + m * 16 + l15;
      aoff[m][kk] = (row * 128 + kk * 64 + loct * 16) ^ ((row & 7) << 4);
    }
#pragma unroll
  for (int n = 0; n < NR; ++n)
#pragma unroll
    for (int kk = 0; kk < 2; ++kk) {
      int nn = wn * (NR * 16) + n * 16 + l15;
      boff[n][kk] = (nn * 128 + kk * 64 + loct * 16) ^ ((nn & 7) << 4);
    }

  f32x4 acc[MR][NR];
#pragma unroll
  for (int m = 0; m < MR; ++m)
#pragma unroll
    for (int n = 0; n < NR; ++n) acc[m][n] = {0.f, 0.f, 0.f, 0.f};

  f32x4 av[12];   // one superstep's A (48 VGPR); av[j*4+i]

  auto issueSuper = [&](int S) {
#pragma unroll
    for (int j = 0; j < 3; ++j)
#pragma unroll
      for (int i = 0; i < 4; ++i)
        av[j * 4 + i] =
            *(const f32x4*)(aptr + S * 192 + j * 64 + i * 16 + q * 4);
  };
  auto glB = [&](int s, int buf) {
#pragma unroll
    for (int j = 0; j < NB; ++j)
      glds16(bptr + (size_t)j * 32 * NROW + s * BK,
             ldsBw + buf * BBYTES + j * 4096);
  };
  auto cvtWrite = [&](int j, int buf) {   // write slice j into A buf
    char* wb = lds + buf * 8192;
#pragma unroll
    for (int i = 0; i < 4; ++i) {
      uint2 w;
      w.x = pk2(av[j * 4 + i].x, av[j * 4 + i].y);
      w.y = pk2(av[j * 4 + i].z, av[j * 4 + i].w);
      *(uint2*)(wb + ((r * 128 + i * 32 + q * 8) ^ sw)) = w;
    }
  };
  auto compute = [&](int buf) {
    const char* lA = lds + buf * 8192;
    const char* lB = ldsB + buf * BBYTES;
#pragma unroll
    for (int kk = 0; kk < 2; ++kk) {
      short8 af[MR], bfv[NR];
#pragma unroll
      for (int m = 0; m < MR; ++m) af[m] = *(const short8*)(lA + aoff[m][kk]);
#pragma unroll
      for (int n = 0; n < NR; ++n) bfv[n] = *(const short8*)(lB + boff[n][kk]);
#pragma unroll
      for (int m = 0; m < MR; ++m)
#pragma unroll
        for (int n = 0; n < NR; ++n)
          acc[m][n] = __builtin_amdgcn_mfma_f32_16x16x32_bf16(
              af[m], bfv[n], acc[m][n], 0, 0, 0);
    }
  };

  // ---- Prologue: set0 burst; B(0) DMA; A slice0 -> buf0 ----
  glB(0, 0);
  __builtin_amdgcn_sched_barrier(0);   // pin: DMAs precede A loads
  issueSuper(0);
  cvtWrite(0, 0);          // compiler waits av arrival
  asm volatile("s_waitcnt vmcnt(0) lgkmcnt(0)" ::: "memory");
  __builtin_amdgcn_s_barrier();
  __builtin_amdgcn_sched_barrier(0);

  for (int S = 0; S < NSUP; ++S) {
    const int b = S & 1;   // parity of step 3S
    // ---- step 3S: stage (3S+1) ----
    glB(3 * S + 1, b ^ 1);
    compute(b);
    cvtWrite(1, b ^ 1);
    asm volatile("s_waitcnt vmcnt(0) lgkmcnt(0)" ::: "memory");
    __builtin_amdgcn_s_barrier();
    __builtin_amdgcn_sched_barrier(0);
    // ---- step 3S+1: stage (3S+2); burst-issue set S+1 ----
    glB(3 * S + 2, b);
    __builtin_amdgcn_sched_barrier(0);   // pin: DMAs before A prefetch
    compute(b ^ 1);
    cvtWrite(2, b);
    if (S + 1 < NSUP) {
      issueSuper(S + 1);   // 12 loads stay in flight across barrier
      asm volatile("s_waitcnt vmcnt(12) lgkmcnt(0)" ::: "memory");
    } else {
      asm volatile("s_waitcnt vmcnt(0) lgkmcnt(0)" ::: "memory");
    }
    __builtin_amdgcn_s_barrier();
    __builtin_amdgcn_sched_barrier(0);
    // ---- step 3S+2: stage (3S+3) from NEW set ----
    if (S + 1 < NSUP) {
      glB(3 * S + 3, b ^ 1);
      compute(b);
      cvtWrite(0, b ^ 1);  // compiler waits new set arrival
      asm volatile("s_waitcnt vmcnt(0) lgkmcnt(0)" ::: "memory");
      __builtin_amdgcn_s_barrier();
      __builtin_amdgcn_sched_barrier(0);
    } else {
      compute(b);          // final step, no staging
    }
  }

  float* pout = part + ((size_t)split * NROW + (size_t)bm * BM) * H;
#pragma unroll
  for (int m = 0; m < MR; ++m) {
    const int row = wm * (MR * 16) + m * 16 + loct * 4;
#pragma unroll
    for (int n = 0; n < NR; ++n) {
      const int col = wn * (NR * 16) + n * 16 + l15;
#pragma unroll
      for (int rr = 0; rr < 4; ++rr)
        pout[(size_t)(row + rr) * H + col] = acc[m][n][rr];
    }
  }
}

// ------- reduce: sum splits + bias + LN + (leaky) + @Wnext -> t_next^T -------
template <int H, int H2, bool ACT>
__global__ __launch_bounds__(256) void reduce_ln(
    const float* __restrict__ part, const float* __restrict__ bias,
    const float* __restrict__ g, const float* __restrict__ be,
    const float* __restrict__ Wn, unsigned short* __restrict__ tT) {
  __shared__ float sW[H * H2];
  __shared__ float sh[4][H];
  const int t = threadIdx.x;
  for (int i = t; i < H * H2; i += 256) sW[i] = Wn[i];
  __syncthreads();

  const int wid = t >> 6, lane = t & 63;
  const int row = blockIdx.x * 4 + wid;
  constexpr int CPL = H / 64;
  float v[CPL];
#pragma unroll
  for (int c = 0; c < CPL; ++c) {
    const int col = lane + c * 64;
    float s = bias[col];
#pragma unroll
    for (int sp = 0; sp < 4; ++sp)
      s += part[((size_t)sp * NROW + row) * H + col];
    v[c] = s;
  }
  float sum = 0;
#pragma unroll
  for (int c = 0; c < CPL; ++c) sum += v[c];
#pragma unroll
  for (int o = 32; o > 0; o >>= 1) sum += __shfl_xor(sum, o);
  const float mu = sum / H;
  float vs = 0;
#pragma unroll
  for (int c = 0; c < CPL; ++c) { float d = v[c] - mu; vs += d * d; }
#pragma unroll
  for (int o = 32; o > 0; o >>= 1) vs += __shfl_xor(vs, o);
  const float rstd = rsqrtf(vs / H + 1e-5f);
#pragma unroll
  for (int c = 0; c < CPL; ++c) {
    const int col = lane + c * 64;
    float h = (v[c] - mu) * rstd * g[col] + be[col];
    if (ACT) h = (h > 0.f) ? h : 0.01f * h;
    sh[wid][col] = h;
  }
  __syncthreads();
  if (lane < H2) {
    float d = 0;
#pragma unroll 8
    for (int k = 0; k < H; ++k) d += sh[wid][k] * sW[k * H2 + lane];
    tT[(size_t)lane * NROW + row] = f2bf(d);
  }
}

// ------- final: sum splits + bias + LN + leaky + @Wl+bl + log_softmax -------
__global__ __launch_bounds__(256) void reduce_final(
    const float* __restrict__ part, const float* __restrict__ bias,
    const float* __restrict__ g, const float* __restrict__ be,
    const float* __restrict__ Wl, const float* __restrict__ bl,
    float* __restrict__ out) {
  __shared__ float sW[32 * 20];
  __shared__ float sbl[20];
  __shared__ float sh[4][32];
  __shared__ float sl[4][20];
  const int t = threadIdx.x;
  for (int i = t; i < 640; i += 256) sW[i] = Wl[i];
  if (t < 20) sbl[t] = bl[t];
  __syncthreads();
  const int wid = t >> 6, lane = t & 63;
  const int row = blockIdx.x * 4 + wid;
  const int col = lane & 31;  // lanes 32..63 duplicate cols 0..31
  float v = bias[col];
#pragma unroll
  for (int sp = 0; sp < 4; ++sp)
    v += part[((size_t)sp * NROW + row) * 32 + col];
  float sum = v;
#pragma unroll
  for (int o = 32; o > 0; o >>= 1) sum += __shfl_xor(sum, o);
  const float mu = sum / 64.f;  // values duplicated 2x across the wave
  float d0 = v - mu;
  float vs = d0 * d0;
#pragma unroll
  for (int o = 32; o > 0; o >>= 1) vs += __shfl_xor(vs, o);
  const float rstd = rsqrtf(vs / 64.f + 1e-5f);
  float h = (v - mu) * rstd * g[col] + be[col];
  h = (h > 0.f) ? h : 0.01f * h;
  if (lane < 32) sh[wid][col] = h;
  __syncthreads();
  if (lane < 20) {
    float lg = sbl[lane];
#pragma unroll
    for (int k = 0; k < 32; ++k) lg += sh[wid][k] * sW[k * 20 + lane];
    sl[wid][lane] = lg;
  }
  __syncthreads();
  if (lane < 20) {
    float mx = -1e30f;
#pragma unroll
    for (int k = 0; k < 20; ++k) mx = fmaxf(mx, sl[wid][k]);
    float se = 0.f;
#pragma unroll
    for (int k = 0; k < 20; ++k) se += expf(sl[wid][k] - mx);
    out[(size_t)row * 20 + lane] = sl[wid][lane] - mx - logf(se);
  }
}

extern "C" void kernel_launch(void* const* d_in, const int* in_sizes, int n_in,
                              void* d_out, int out_size, void* d_ws,
                              size_t ws_size, hipStream_t stream) {
  const float* x    = (const float*)d_in[0];
  const float* adj0 = (const float*)d_in[1];
  const float* adj1 = (const float*)d_in[2];
  const float* adj2 = (const float*)d_in[3];
  const float* W0   = (const float*)d_in[4];
  const float* b0   = (const float*)d_in[5];
  const float* W1   = (const float*)d_in[6];
  const float* b1   = (const float*)d_in[7];
  const float* W2   = (const float*)d_in[8];
  const float* b2   = (const float*)d_in[9];
  const float* g0   = (const float*)d_in[10];
  const float* be0  = (const float*)d_in[11];
  const float* g1   = (const float*)d_in[12];
  const float* be1  = (const float*)d_in[13];
  const float* g2   = (const float*)d_in[14];
  const float* be2  = (const float*)d_in[15];
  const float* Wl   = (const float*)d_in[16];
  const float* bl   = (const float*)d_in[17];
  float* out = (float*)d_out;

  char* ws = (char*)d_ws;
  float* part =          (float*)(ws);                      // 4*12288*128*4 = 25165824 B
  unsigned short* t0T = (unsigned short*)(ws + 25165824);   // 128*12288*2 = 3145728 B
  unsigned short* t1T = (unsigned short*)(ws + 25165824 + 3145728);          // 1572864 B
  unsigned short* t2T = (unsigned short*)(ws + 25165824 + 3145728 + 1572864); // 786432 B

  xw_kernel<<<NROW / 16, 256, 0, stream>>>(x, W0, t0T);
  gcn_gemm<128><<<(NROW / 64) * 4, 256, 0, stream>>>(adj0, t0T, part);
  reduce_ln<128, 64, false><<<NROW / 4, 256, 0, stream>>>(part, b0, g0, be0, W1, t1T);
  gcn_gemm<64><<<(NROW / 64) * 4, 256, 0, stream>>>(adj1, t1T, part);
  reduce_ln<64, 32, true><<<NROW / 4, 256, 0, stream>>>(part, b1, g1, be1, W2, t2T);
  gcn_gemm<32><<<(NROW / 64) * 4, 256, 0, stream>>>(adj2, t2T, part);
  reduce_final<<<NROW / 4, 256, 0, stream>>>(part, b2, g2, be2, Wl, bl, out);
}